// Round 5
// baseline (153.075 us; speedup 1.0000x reference)
//
#include <hip/hip_runtime.h>

// filtered_lrelu: 2x FIR up (12 taps) -> lrelu(0.01) -> 2x FIR down (12 taps)
// x: [8,128,130,130] f32, filters: 12 f32, out: [8,128,128,128] f32.
//
// Gain: both 2x factors folded into the up filter (fu2 = 2*fu, used in stage A
// horizontally and stage B vertically => x4 total) -- exact since
// lrelu(s*z)=s*lrelu(z) for s>0. fd = downf reversed, raw s_loads -> SGPRs.
//
// v6: tile 26x64 (5 x-tiles of 26 cover 130>=128; last tile stores 24 cols).
//   u/w column count = 2*26+12 = 64  => stage B is EXACTLY 2 full waves
//   (2 segs x 64 cols = 128 threads x 37 steps), eliminating the 24/64-lane
//   partial wave of the 76-col layout (-33% stage-B wave issue).
//   LDS = 74*64*4 = 18944 B -> 8 blocks/CU (32 waves, occupancy cap 100%).
//   stage A: global -> u[74][64] horiz up-conv, 16 quads x 16 rows x 5 rounds.
//   stage B: vert up + lrelu + vert down, macro-unrolled, w aliases u
//            (seg0 w rows 0..31 -> slots 0..31, seg1 rows 32..63 -> 42..73;
//            columns thread-private => same-thread program order suffices).
//   stage C: 832 tasks (64 rows x 13 col-pairs), w base col 4j (16B aligned),
//            float2 stores with right-edge guard.

#define TOX 26
#define TOY 64
#define UST 64          // u/w row stride (floats)
#define U_ROWS 74       // TOY + 10

template <bool COLSAFE>
__device__ __forceinline__ void stage_a(const float* __restrict__ xc,
                                        float* __restrict__ u_sh,
                                        const float* __restrict__ fu2,
                                        int tid, int ox0, int oy0) {
    const int g   = tid & 15;            // u quad: cols 4g..4g+3
    const int h0  = tid >> 4;            // 0..15
    const int gc0 = ox0 - 4 + 2 * g;     // x col of s0
    bool c0 = true, c2 = true, c4 = true, c6 = true;
    int  o0 = gc0, o2 = gc0 + 2, o4 = gc0 + 4, o6 = gc0 + 6;
    if (!COLSAFE) {
        c0 = (unsigned)(gc0    ) <= 128u; o0 = c0 ? gc0     : 0;
        c2 = (unsigned)(gc0 + 2) <= 128u; o2 = c2 ? gc0 + 2 : 0;
        c4 = (unsigned)(gc0 + 4) <= 128u; o4 = c4 ? gc0 + 4 : 0;
        c6 = (unsigned)(gc0 + 6) <= 129u; o6 = c6 ? gc0 + 6 : 0;
    }
#pragma unroll
    for (int k = 0; k < 5; ++k) {
        const int h = h0 + 16 * k;
        if (k < 4 || h < U_ROWS) {       // k=4 active for h0 < 10
            const int gr = oy0 - 4 + h;
            // row OOB only: round 0 on top tile, round 4 on bottom tile
            const bool mayclip = (k == 0 && oy0 == 0) || (k == 4 && oy0 != 0);
            bool rok = true;
            int  grc = gr;
            if (mayclip) { rok = (unsigned)gr < 130u; grc = rok ? gr : 0; }
            const float* __restrict__ xr = xc + grc * 130;
            float2 t01 = *(const float2*)(xr + o0);
            float2 t23 = *(const float2*)(xr + o2);
            float2 t45 = *(const float2*)(xr + o4);
            float  t6  = xr[o6];
            float s0 = t01.x, s1 = t01.y, s2 = t23.x, s3 = t23.y,
                  s4 = t45.x, s5 = t45.y, s6 = t6;
            if (!COLSAFE) {
                s0 = c0 ? s0 : 0.f; s1 = c0 ? s1 : 0.f;
                s2 = c2 ? s2 : 0.f; s3 = c2 ? s3 : 0.f;
                s4 = c4 ? s4 : 0.f; s5 = c4 ? s5 : 0.f;
                s6 = c6 ? s6 : 0.f;
            }
            float u0 = fu2[0]*s5 + fu2[2]*s4 + fu2[4]*s3 + fu2[6]*s2 + fu2[8]*s1 + fu2[10]*s0;
            float u1 = fu2[1]*s5 + fu2[3]*s4 + fu2[5]*s3 + fu2[7]*s2 + fu2[9]*s1 + fu2[11]*s0;
            float u2 = fu2[0]*s6 + fu2[2]*s5 + fu2[4]*s4 + fu2[6]*s3 + fu2[8]*s2 + fu2[10]*s1;
            float u3 = fu2[1]*s6 + fu2[3]*s5 + fu2[5]*s4 + fu2[7]*s3 + fu2[9]*s2 + fu2[11]*s1;
            if (mayclip && !rok) { u0 = 0.f; u1 = 0.f; u2 = 0.f; u3 = 0.f; }
            *(float4*)(u_sh + h * UST + 4 * g) = make_float4(u0, u1, u2, u3);
        }
    }
}

__global__ __launch_bounds__(256, 8)
void flrelu_fused_kernel(const float* __restrict__ x,
                         const float* __restrict__ upf,
                         const float* __restrict__ downf,
                         float* __restrict__ out) {
    __shared__ __align__(16) float u_s[U_ROWS * UST];   // 18944 B

    const int tid = threadIdx.x;
    const int ch  = blockIdx.z;
    const int ox0 = blockIdx.x * TOX;    // 0,26,52,78,104
    const int oy0 = blockIdx.y * TOY;

    // fu2 = 2*up (VGPR, one v_mul each); fd = down reversed (pure s_load).
    float fu2[12], fd[12];
#pragma unroll
    for (int t = 0; t < 12; ++t) fu2[t] = 2.0f * upf[t];
#pragma unroll
    for (int t = 0; t < 12; ++t) fd[t] = downf[11 - t];

    // ---- stage A: global -> u (horizontal up-conv x 2fu), rows 0..73 ----
    {
        const float* __restrict__ xc = x + (size_t)ch * (130 * 130);
        // colsafe iff ox0-4 >= 0 and ox0+32 <= 129  -> interior tiles 1..3
        if (ox0 == 0 || ox0 > 97)
            stage_a<false>(xc, u_s, fu2, tid, ox0, oy0);
        else
            stage_a<true>(xc, u_s, fu2, tid, ox0, oy0);
    }
    __syncthreads();

    // ---- stage B: vert up (x 2fu) + lrelu + vert down, fused sliding ----
    // 128 tasks = 2 FULL waves: seg = tid>>6 (32 out rows each), col = tid&63.
    // 37 macro-unrolled steps, compile-time LDS offsets.
    // w ALIASES u: seg0 w rows 0..31 -> slots 0..31 (disjoint from seg1 reads
    // 32..73); seg1 w rows 32..63 -> slots 42..73 (disjoint from seg0 reads
    // 0..41). Columns thread-private => same-thread program order suffices.
    if (tid < 128) {
        const int seg = tid >> 6;
        const int lj  = tid & 63;
        const float* ucol = u_s + (seg * 32) * UST + lj;
        float*       wb   = u_s + (seg * 42) * UST + lj;
        float rA = ucol[0*UST], rB = ucol[1*UST], rC = ucol[2*UST],
              rD = ucol[3*UST], rE = ucol[4*UST], rF;
        float wA = 0.f, wB = 0.f, wC = 0.f, wD = 0.f, wE = 0.f, wF = 0.f;

        // STEP(m, r0..r5=rows m..m+5 (r5 loaded), w0=row m (new) .. w5=row m-5)
#define STEP(m, r0_,r1_,r2_,r3_,r4_,r5_, w0_,w1_,w2_,w3_,w4_,w5_)              \
        {                                                                      \
            r5_ = ucol[(m + 5) * UST];                                         \
            float z0 = fu2[0]*r5_ + fu2[2]*r4_ + fu2[4]*r3_ + fu2[6]*r2_       \
                     + fu2[8]*r1_ + fu2[10]*r0_;                               \
            float z1 = fu2[1]*r5_ + fu2[3]*r4_ + fu2[5]*r3_ + fu2[7]*r2_       \
                     + fu2[9]*r1_ + fu2[11]*r0_;                               \
            z0 = fmaxf(z0, 0.01f * z0);                                        \
            z1 = fmaxf(z1, 0.01f * z1);                                        \
            w0_ = fmaf(fd[0], z0, fd[1] * z1);                                 \
            w1_ = fmaf(fd[2],  z0, fmaf(fd[3],  z1, w1_));                     \
            w2_ = fmaf(fd[4],  z0, fmaf(fd[5],  z1, w2_));                     \
            w3_ = fmaf(fd[6],  z0, fmaf(fd[7],  z1, w3_));                     \
            w4_ = fmaf(fd[8],  z0, fmaf(fd[9],  z1, w4_));                     \
            w5_ = fmaf(fd[10], z0, fmaf(fd[11], z1, w5_));                     \
            if ((m) >= 5) wb[((m) - 5) * UST] = w5_;                           \
        }
#define S6(m0)                                                                 \
        STEP(m0+0, rA,rB,rC,rD,rE,rF, wA,wF,wE,wD,wC,wB)                       \
        STEP(m0+1, rB,rC,rD,rE,rF,rA, wB,wA,wF,wE,wD,wC)                       \
        STEP(m0+2, rC,rD,rE,rF,rA,rB, wC,wB,wA,wF,wE,wD)                       \
        STEP(m0+3, rD,rE,rF,rA,rB,rC, wD,wC,wB,wA,wF,wE)                       \
        STEP(m0+4, rE,rF,rA,rB,rC,rD, wE,wD,wC,wB,wA,wF)                       \
        STEP(m0+5, rF,rA,rB,rC,rD,rE, wF,wE,wD,wC,wB,wA)

        S6(0) S6(6) S6(12) S6(18) S6(24) S6(30)
        STEP(36, rA,rB,rC,rD,rE,rF, wA,wF,wE,wD,wC,wB)
#undef S6
#undef STEP
    }
    __syncthreads();

    // ---- stage C: horizontal down-conv: w -> out 26x64 ----
    // 832 tasks = 64 rows x 13 col-pairs; task -> oy = task/13, j = task%13.
    // Outputs (tile-rel) cols 2j, 2j+1 from w cols 4j..4j+13 (16B aligned).
    // w row oy at u slot oy (+10 if oy>=32). Right-edge guard for last tile.
    {
        float* __restrict__ outc = out + (size_t)ch * (128 * 128);
#pragma unroll
        for (int k = 0; k < 4; ++k) {
            const int task = tid + 256 * k;
            if (k < 3 || task < 832) {
                const int oy   = task / 13;
                const int j    = task - 13 * oy;
                const int slot = oy + ((oy >= 32) ? 10 : 0);
                const float* wr = u_s + slot * UST + 4 * j;
                float4 q0 = *(const float4*)&wr[0];
                float4 q1 = *(const float4*)&wr[4];
                float4 q2 = *(const float4*)&wr[8];
                float2 e  = *(const float2*)&wr[12];
                float o0v = fd[0]*q0.x + fd[1]*q0.y + fd[2]*q0.z + fd[3]*q0.w
                          + fd[4]*q1.x + fd[5]*q1.y + fd[6]*q1.z + fd[7]*q1.w
                          + fd[8]*q2.x + fd[9]*q2.y + fd[10]*q2.z + fd[11]*q2.w;
                float o1v = fd[0]*q0.z + fd[1]*q0.w + fd[2]*q1.x + fd[3]*q1.y
                          + fd[4]*q1.z + fd[5]*q1.w + fd[6]*q2.x + fd[7]*q2.y
                          + fd[8]*q2.z + fd[9]*q2.w + fd[10]*e.x  + fd[11]*e.y;
                const int oc = ox0 + 2 * j;
                if (oc < 128)
                    *(float2*)(outc + (size_t)(oy0 + oy) * 128 + oc) =
                        make_float2(o0v, o1v);
            }
        }
    }
}

extern "C" void kernel_launch(void* const* d_in, const int* in_sizes, int n_in,
                              void* d_out, int out_size, void* d_ws, size_t ws_size,
                              hipStream_t stream) {
    const float* x     = (const float*)d_in[0];
    const float* upf   = (const float*)d_in[1];
    const float* downf = (const float*)d_in[2];
    float* out = (float*)d_out;

    dim3 grid(5, 128 / TOY, 8 * 128);   // 5 x 2 x 1024
    dim3 block(256);
    flrelu_fused_kernel<<<grid, block, 0, stream>>>(x, upf, downf, out);
}

// Round 6
// 149.813 us; speedup vs baseline: 1.0218x; 1.0218x over previous
//
#include <hip/hip_runtime.h>

// filtered_lrelu: 2x FIR up (12 taps) -> lrelu(0.01) -> 2x FIR down (12 taps)
// x: [8,128,130,130] f32, filters: 12 f32, out: [8,128,128,128] f32.
//
// v7 = v5 geometry (tile 32x64, UST=76 non-pow2, 22496 B LDS, 7 blocks/CU,
// clean float4 output stores) + packed-FP32 (v_pk_fma_f32) math:
//   - filters are symmetric (h[i]==h[11-i], ulp-exact by construction):
//     only 6 unique coeffs per filter, kept as wave-uniform scalars (SGPR).
//   - gain (x4 vs raw up/down filters) applied once at the final store with
//     the inline constant 4.0 -- exact: lrelu(s*z)=s*lrelu(z), rest linear.
//   - stage B: each thread owns TWO adjacent u-columns as a v2f. LDS ops are
//     ds_read_b64/ds_write_b64 of natural pairs; 24 FMA/step -> 12 pk_fma.
//     152 -> 76 threads: 2 waves x 37 steps (-33% stage-B wave issue).
//   - stage C: phase-pair packing, 48 FMA -> 24 pk_fma + 4 pair-reduces.
//   - stage A: scalar (unchanged structure), coeffs now SGPR.

typedef float v2f __attribute__((ext_vector_type(2)));

#define TOX 32
#define TOY 64
#define UST 76          // u/w row stride (floats); non-pow2 => bank spread
#define U_ROWS 74       // TOY + 10

#define VFMA(a, b, c) __builtin_elementwise_fma((a), (b), (c))
#define VMAX(a, b)    __builtin_elementwise_max((a), (b))

__device__ __forceinline__ v2f vsp(float s) { return (v2f){s, s}; }

template <bool COLSAFE>
__device__ __forceinline__ void stage_a(const float* __restrict__ xc,
                                        float* __restrict__ u_sh,
                                        float e0, float e1, float e2,
                                        float e3, float e4, float e5,
                                        int tid, int ox0, int oy0) {
    const int g   = tid % 19;
    const int h0  = tid / 19;            // 0..12 for tid<247
    const int gc0 = ox0 - 4 + 2 * g;
    bool c0 = true, c2 = true, c4 = true, c6 = true;
    int  o0 = gc0, o2 = gc0 + 2, o4 = gc0 + 4, o6 = gc0 + 6;
    if (!COLSAFE) {
        c0 = (unsigned)(gc0    ) <= 128u; o0 = c0 ? gc0     : 0;
        c2 = (unsigned)(gc0 + 2) <= 128u; o2 = c2 ? gc0 + 2 : 0;
        c4 = (unsigned)(gc0 + 4) <= 128u; o4 = c4 ? gc0 + 4 : 0;
        c6 = (unsigned)(gc0 + 6) <= 129u; o6 = c6 ? gc0 + 6 : 0;
    }
    if (tid < 247) {
#pragma unroll
        for (int k = 0; k < 6; ++k) {
            const int h = h0 + 13 * k;
            if (k < 5 || h < U_ROWS) {
                const int gr = oy0 - 4 + h;
                // rows OOB only: round 0 on top tile, round 5 on bottom tile
                const bool mayclip = (k == 0 && oy0 == 0) || (k == 5 && oy0 != 0);
                bool rok = true;
                int  grc = gr;
                if (mayclip) { rok = (unsigned)gr < 130u; grc = rok ? gr : 0; }
                const float* __restrict__ xr = xc + grc * 130;
                float2 t01 = *(const float2*)(xr + o0);
                float2 t23 = *(const float2*)(xr + o2);
                float2 t45 = *(const float2*)(xr + o4);
                float  t6  = xr[o6];
                float s0 = t01.x, s1 = t01.y, s2 = t23.x, s3 = t23.y,
                      s4 = t45.x, s5 = t45.y, s6 = t6;
                if (!COLSAFE) {
                    s0 = c0 ? s0 : 0.f; s1 = c0 ? s1 : 0.f;
                    s2 = c2 ? s2 : 0.f; s3 = c2 ? s3 : 0.f;
                    s4 = c4 ? s4 : 0.f; s5 = c4 ? s5 : 0.f;
                    s6 = c6 ? s6 : 0.f;
                }
                // symmetric filter: odd-phase coeffs are e5..e0 reversed
                float u0 = e0*s5 + e1*s4 + e2*s3 + e3*s2 + e4*s1 + e5*s0;
                float u1 = e5*s5 + e4*s4 + e3*s3 + e2*s2 + e1*s1 + e0*s0;
                float u2 = e0*s6 + e1*s5 + e2*s4 + e3*s3 + e4*s2 + e5*s1;
                float u3 = e5*s6 + e4*s5 + e3*s4 + e2*s3 + e1*s2 + e0*s1;
                if (mayclip && !rok) { u0 = 0.f; u1 = 0.f; u2 = 0.f; u3 = 0.f; }
                *(float4*)(u_sh + h * UST + 4 * g) = make_float4(u0, u1, u2, u3);
            }
        }
    }
}

__global__ __launch_bounds__(256, 7)
void flrelu_fused_kernel(const float* __restrict__ x,
                         const float* __restrict__ upf,
                         const float* __restrict__ downf,
                         float* __restrict__ out) {
    __shared__ __align__(16) float u_s[U_ROWS * UST];   // 22496 B

    const int tid = threadIdx.x;
    const int ch  = blockIdx.z;
    const int ox0 = blockIdx.x * TOX;
    const int oy0 = blockIdx.y * TOY;

    // Symmetric 12-tap filters: 6 unique coeffs each (uniform -> SGPR).
    const float e0 = upf[0],   e1 = upf[2],   e2 = upf[4],
                e3 = upf[6],   e4 = upf[8],   e5 = upf[10];
    const float d0 = downf[0], d1 = downf[1], d2 = downf[2],
                d3 = downf[3], d4 = downf[4], d5 = downf[5];

    // ---- stage A: global -> u (horizontal up-conv, raw gain), rows 0..73 ----
    {
        const float* __restrict__ xc = x + (size_t)ch * (130 * 130);
        if (ox0 == 0 || ox0 + TOX == 128)
            stage_a<false>(xc, u_s, e0, e1, e2, e3, e4, e5, tid, ox0, oy0);
        else
            stage_a<true>(xc, u_s, e0, e1, e2, e3, e4, e5, tid, ox0, oy0);
    }
    __syncthreads();

    // ---- stage B: vert up + lrelu + vert down, packed column-pairs ----
    // 76 tasks (2 waves): seg = tid>=38 (32 out rows each), pair p = 0..37
    // owning u cols 2p, 2p+1 as one v2f. 37 macro-unrolled steps.
    // w ALIASES u exactly as v5: seg0 w rows 0..31 -> slots 0..31 (disjoint
    // from seg1 reads 32..73); seg1 w rows -> slots 42..73 (write = the row
    // just read this step). Column-pairs thread-private => program order.
    if (tid < 76) {
        const int seg = (tid >= 38) ? 1 : 0;
        const int p   = tid - 38 * seg;
        const float* ucol = u_s + (seg * 32) * UST + 2 * p;
        float*       wout = u_s + (seg * 42) * UST + 2 * p;
        v2f rA = *(const v2f*)(ucol + 0*UST), rB = *(const v2f*)(ucol + 1*UST),
            rC = *(const v2f*)(ucol + 2*UST), rD = *(const v2f*)(ucol + 3*UST),
            rE = *(const v2f*)(ucol + 4*UST), rF;
        v2f wA = vsp(0.f), wB = vsp(0.f), wC = vsp(0.f),
            wD = vsp(0.f), wE = vsp(0.f), wF = vsp(0.f);

        // STEP(m, r0..r5=rows m..m+5 (r5 loaded), w0=row m (new) .. w5=retire)
#define STEP(m, r0_,r1_,r2_,r3_,r4_,r5_, w0_,w1_,w2_,w3_,w4_,w5_)              \
        {                                                                      \
            r5_ = *(const v2f*)(ucol + (m + 5) * UST);                         \
            v2f z0 = VFMA(vsp(e0), r5_, VFMA(vsp(e1), r4_, VFMA(vsp(e2), r3_, \
                     VFMA(vsp(e3), r2_, VFMA(vsp(e4), r1_, vsp(e5)*r0_)))));   \
            v2f z1 = VFMA(vsp(e5), r5_, VFMA(vsp(e4), r4_, VFMA(vsp(e3), r3_, \
                     VFMA(vsp(e2), r2_, VFMA(vsp(e1), r1_, vsp(e0)*r0_)))));   \
            z0 = VMAX(z0, 0.01f * z0);                                         \
            z1 = VMAX(z1, 0.01f * z1);                                         \
            w0_ = VFMA(vsp(d0), z0, vsp(d1) * z1);                             \
            w1_ = VFMA(vsp(d2), z0, VFMA(vsp(d3), z1, w1_));                   \
            w2_ = VFMA(vsp(d4), z0, VFMA(vsp(d5), z1, w2_));                   \
            w3_ = VFMA(vsp(d5), z0, VFMA(vsp(d4), z1, w3_));                   \
            w4_ = VFMA(vsp(d3), z0, VFMA(vsp(d2), z1, w4_));                   \
            w5_ = VFMA(vsp(d1), z0, VFMA(vsp(d0), z1, w5_));                   \
            if ((m) >= 5) *(v2f*)(wout + ((m) - 5) * UST) = w5_;               \
        }
#define S6(m0)                                                                 \
        STEP(m0+0, rA,rB,rC,rD,rE,rF, wA,wF,wE,wD,wC,wB)                       \
        STEP(m0+1, rB,rC,rD,rE,rF,rA, wB,wA,wF,wE,wD,wC)                       \
        STEP(m0+2, rC,rD,rE,rF,rA,rB, wC,wB,wA,wF,wE,wD)                       \
        STEP(m0+3, rD,rE,rF,rA,rB,rC, wD,wC,wB,wA,wF,wE)                       \
        STEP(m0+4, rE,rF,rA,rB,rC,rD, wE,wD,wC,wB,wA,wF)                       \
        STEP(m0+5, rF,rA,rB,rC,rD,rE, wF,wE,wD,wC,wB,wA)

        S6(0) S6(6) S6(12) S6(18) S6(24) S6(30)
        STEP(36, rA,rB,rC,rD,rE,rF, wA,wF,wE,wD,wC,wB)
#undef S6
#undef STEP
    }
    __syncthreads();

    // ---- stage C: horizontal down-conv (packed phase-pairs) -> out 32x64 ----
    // 2 rounds x 256 tasks: oy = oyr*32 + (tid>>3), g = tid&7; reads w pairs
    // v0..v8 = w[8g..8g+17]; o_k = 4 * hsum( sum_j FD_j (*) v_{k+j} ).
    {
        const int g = tid & 7;
        const int t = tid >> 3;
        const v2f D01 = {d0, d1}, D23 = {d2, d3}, D45 = {d4, d5},
                  D54 = {d5, d4}, D32 = {d3, d2}, D10 = {d1, d0};
        float* __restrict__ outc = out + (size_t)ch * (128 * 128);
#pragma unroll
        for (int oyr = 0; oyr < 2; ++oyr) {
            const float* wr = u_s + (oyr * 42 + t) * UST + 8 * g;
            v2f v0 = *(const v2f*)(wr + 0),  v1 = *(const v2f*)(wr + 2),
                v2 = *(const v2f*)(wr + 4),  v3 = *(const v2f*)(wr + 6),
                v4 = *(const v2f*)(wr + 8),  v5 = *(const v2f*)(wr + 10),
                v6 = *(const v2f*)(wr + 12), v7 = *(const v2f*)(wr + 14),
                v8 = *(const v2f*)(wr + 16);
            v2f P0 = VFMA(D01,v0, VFMA(D23,v1, VFMA(D45,v2,
                     VFMA(D54,v3, VFMA(D32,v4, D10*v5)))));
            v2f P1 = VFMA(D01,v1, VFMA(D23,v2, VFMA(D45,v3,
                     VFMA(D54,v4, VFMA(D32,v5, D10*v6)))));
            v2f P2 = VFMA(D01,v2, VFMA(D23,v3, VFMA(D45,v4,
                     VFMA(D54,v5, VFMA(D32,v6, D10*v7)))));
            v2f P3 = VFMA(D01,v3, VFMA(D23,v4, VFMA(D45,v5,
                     VFMA(D54,v6, VFMA(D32,v7, D10*v8)))));
            float o0v = 4.0f * (P0.x + P0.y);
            float o1v = 4.0f * (P1.x + P1.y);
            float o2v = 4.0f * (P2.x + P2.y);
            float o3v = 4.0f * (P3.x + P3.y);
            *(float4*)(outc + (size_t)(oy0 + oyr * 32 + t) * 128 + ox0 + 4 * g) =
                make_float4(o0v, o1v, o2v, o3v);
        }
    }
}

extern "C" void kernel_launch(void* const* d_in, const int* in_sizes, int n_in,
                              void* d_out, int out_size, void* d_ws, size_t ws_size,
                              hipStream_t stream) {
    const float* x     = (const float*)d_in[0];
    const float* upf   = (const float*)d_in[1];
    const float* downf = (const float*)d_in[2];
    float* out = (float*)d_out;

    dim3 grid(128 / TOX, 128 / TOY, 8 * 128);   // 4 x 2 x 1024
    dim3 block(256);
    flrelu_fused_kernel<<<grid, block, 0, stream>>>(x, upf, downf, out);
}